// Round 1
// baseline (10207.763 us; speedup 1.0000x reference)
//
#include <hip/hip_runtime.h>
#include <hip/hip_fp16.h>
#include <math.h>

typedef _Float16 half8 __attribute__((ext_vector_type(8)));
typedef float floatx4 __attribute__((ext_vector_type(4)));

#define NB 64
#define LQ 512
#define HD 1024

__device__ inline half8 cvt2(const float4 a, const float4 b) {
  half8 h;
  h[0]=(_Float16)a.x; h[1]=(_Float16)a.y; h[2]=(_Float16)a.z; h[3]=(_Float16)a.w;
  h[4]=(_Float16)b.x; h[5]=(_Float16)b.y; h[6]=(_Float16)b.z; h[7]=(_Float16)b.w;
  return h;
}

// ---------------------------------------------------------------------------
// GEMM1: d_out[m][o] = sum_k f16(emb[x[m]][k]) * f16(Wxh[o][k]) + bxh[o] + bhh[o]
// m = n*512 + t  (32768 rows). 128x128 tile, BK=64, mfma_f32_16x16x32_f16.
// ---------------------------------------------------------------------------
__global__ __launch_bounds__(256) void gemm1_kernel(
    const int* __restrict__ x, const float* __restrict__ emb,
    const float* __restrict__ Wxh, const float* __restrict__ bxh,
    const float* __restrict__ bhh, float* __restrict__ out)
{
  // +8 f16 pad -> row stride 144 B = 36 words; 36%32=4 -> 2-way bank alias (free)
  __shared__ alignas(16) _Float16 As[128][72];
  __shared__ alignas(16) _Float16 Bs[128][72];
  const int tid  = threadIdx.x;
  const int lane = tid & 63, wv = tid >> 6;
  const int wm = wv & 1, wn = wv >> 1;          // 2x2 waves of 64x64
  const int Mbase = blockIdx.x * 128;
  const int Nbase = blockIdx.y * 128;

  const int srow  = tid >> 1;                   // staging row 0..127
  const int shalf = tid & 1;                    // k half 0..31 / 32..63
  const size_t erow = (size_t)x[Mbase + srow] * HD;  // gathered embedding row
  const size_t brow = (size_t)(Nbase + srow) * HD;

  floatx4 acc[4][4];
#pragma unroll
  for (int i = 0; i < 4; i++)
#pragma unroll
    for (int j = 0; j < 4; j++) acc[i][j] = (floatx4)0.f;

  for (int c = 0; c < 16; ++c) {               // K = 1024, BK = 64
    const int k0 = c * 64 + shalf * 32;
    const float4* ap = (const float4*)(emb + erow + k0);
    const float4* bp = (const float4*)(Wxh + brow + k0);
    float4 av[8], bv[8];
#pragma unroll
    for (int i = 0; i < 8; i++) { av[i] = ap[i]; bv[i] = bp[i]; }
    __syncthreads();                            // previous iter's readers done
#pragma unroll
    for (int i = 0; i < 4; i++) {
      *(half8*)&As[srow][shalf*32 + i*8] = cvt2(av[2*i], av[2*i+1]);
      *(half8*)&Bs[srow][shalf*32 + i*8] = cvt2(bv[2*i], bv[2*i+1]);
    }
    __syncthreads();
#pragma unroll
    for (int s = 0; s < 2; ++s) {
      const int koff = s*32 + (lane >> 4) * 8;
      half8 af[4], bf[4];
#pragma unroll
      for (int i = 0; i < 4; i++) {
        af[i] = *(const half8*)&As[wm*64 + i*16 + (lane & 15)][koff];
        bf[i] = *(const half8*)&Bs[wn*64 + i*16 + (lane & 15)][koff];
      }
#pragma unroll
      for (int i = 0; i < 4; i++)
#pragma unroll
        for (int j = 0; j < 4; j++)
          acc[i][j] = __builtin_amdgcn_mfma_f32_16x16x32_f16(af[i], bf[j], acc[i][j], 0, 0, 0);
    }
  }
  // epilogue: + biases, fp32 store. C/D layout: col=lane&15, row=(lane>>4)*4+r
#pragma unroll
  for (int j = 0; j < 4; j++) {
    const int o = Nbase + wn*64 + j*16 + (lane & 15);
    const float bias = bxh[o] + bhh[o];
#pragma unroll
    for (int i = 0; i < 4; i++) {
      const int mb = Mbase + wm*64 + i*16 + ((lane >> 4) * 4);
#pragma unroll
      for (int r = 0; r < 4; r++)
        out[(size_t)(mb + r) * HD + o] = acc[i][j][r] + bias;
    }
  }
}

// ---------------------------------------------------------------------------
// Persistent recurrence kernel: 64 wgs x 256 thr. wg j owns output channels
// [16j,16j+16). W_hh slice f16 in LDS (loaded once). h ping-pongs (f16) in ws.
// Per step: flag-barrier -> acquire fence -> 32 mfma k-steps -> tanh ->
// write d_out (fp32) + h (f16) -> release fence -> flag store.
// ---------------------------------------------------------------------------
__global__ __launch_bounds__(256) void rnn_kernel(
    const float* __restrict__ Whh, float* __restrict__ out,
    _Float16* __restrict__ hb, int* __restrict__ flags)
{
  // +8 f16 pad -> row stride 2064 B = 516 words; 516%32=4 -> 2-way alias (free)
  __shared__ alignas(16) _Float16 Ws[16][1032];
  const int tid  = threadIdx.x;
  const int lane = tid & 63;
  const int wv   = tid >> 6;          // m-tile (batch 16-row group)
  const int j    = blockIdx.x;        // channel slice
  const int obase = j * 16;
  const int col  = lane & 15;
  const int quad = lane >> 4;

  { // stage W_hh slice: 16 rows x 1024 k, fp32 -> f16
    const int o = tid >> 4, seg = tid & 15;
    const float4* wp = (const float4*)(Whh + (size_t)(obase + o) * HD + seg * 64);
#pragma unroll
    for (int i = 0; i < 16; i++) {
      float4 w4 = wp[i];
      _Float16* d = &Ws[o][seg*64 + i*4];
      d[0]=(_Float16)w4.x; d[1]=(_Float16)w4.y; d[2]=(_Float16)w4.z; d[3]=(_Float16)w4.w;
    }
  }

  // t = 0: h0 = tanh(xh0)  (h_{-1} = 0, no matmul, no flags needed yet)
#pragma unroll
  for (int r = 0; r < 4; r++) {
    const int n = wv*16 + quad*4 + r;
    const size_t oi = ((size_t)n * LQ + 0) * HD + obase + col;
    float h = tanhf(out[oi]);
    out[oi] = h;
    hb[n * HD + obase + col] = (_Float16)h;
  }
  __threadfence();                    // make h0 + agent-visible (L2 writeback)
  __syncthreads();
  if (tid == 0)
    __hip_atomic_store(&flags[j*32], 1, __ATOMIC_RELEASE, __HIP_MEMORY_SCOPE_AGENT);

  for (int t = 1; t < LQ; ++t) {
    // ---- wait: all wgs finished step t-1 (flags poisoned 0xAA.. = negative)
    if (wv == 0) {
      int spins = 0;
      for (;;) {
        int v = __hip_atomic_load(&flags[lane*32], __ATOMIC_RELAXED, __HIP_MEMORY_SCOPE_AGENT);
        if (__all(v >= t)) break;
        if (++spins > (1 << 22)) break;   // safety valve: wrong > hung
      }
    }
    __syncthreads();
    __threadfence();                  // acquire side: invalidate L1/L2

    // ---- compute: acc = h_prev(16 rows of wv-tile) @ Ws^T
    const _Float16* hprev = hb + (size_t)((t - 1) & 1) * (NB * HD);
    const _Float16* arow  = hprev + (size_t)(wv*16 + col) * HD + quad*8;
    const _Float16* brow  = &Ws[col][quad*8];
    floatx4 acc = (floatx4)0.f;
#pragma unroll 8
    for (int c = 0; c < 32; ++c) {
      half8 a = *(const half8*)(arow + c*32);   // A[m=col][k]
      half8 b = *(const half8*)(brow + c*32);   // B[k][n=col] = Whh[o][k]
      acc = __builtin_amdgcn_mfma_f32_16x16x32_f16(a, b, acc, 0, 0, 0);
    }

    // ---- epilogue: h = tanh(acc + xh) ; xh lives in d_out, overwrite with h
    _Float16* hcur = hb + (size_t)(t & 1) * (NB * HD);
#pragma unroll
    for (int r = 0; r < 4; r++) {
      const int n = wv*16 + quad*4 + r;
      const size_t oi = ((size_t)n * LQ + t) * HD + obase + col;
      float h = tanhf(acc[r] + out[oi]);
      out[oi] = h;
      hcur[n * HD + obase + col] = (_Float16)h;
    }
    __threadfence();                  // release side: writeback before flag
    __syncthreads();
    if (tid == 0)
      __hip_atomic_store(&flags[j*32], t + 1, __ATOMIC_RELEASE, __HIP_MEMORY_SCOPE_AGENT);
  }
}

extern "C" void kernel_launch(void* const* d_in, const int* in_sizes, int n_in,
                              void* d_out, int out_size, void* d_ws, size_t ws_size,
                              hipStream_t stream) {
  // setup_inputs order: x, emb, W_hh_w, W_hh_b, W_xh_w, W_xh_b
  const int*   x   = (const int*)d_in[0];
  const float* emb = (const float*)d_in[1];
  const float* Whh = (const float*)d_in[2];
  const float* bhh = (const float*)d_in[3];
  const float* Wxh = (const float*)d_in[4];
  const float* bxh = (const float*)d_in[5];
  float* out = (float*)d_out;

  _Float16* hb  = (_Float16*)d_ws;                        // 2 x 64 x 1024 f16 = 256 KB
  int*      fl  = (int*)((char*)d_ws + 512 * 1024);       // 64 flags, 128 B apart

  gemm1_kernel<<<dim3(256, 8), 256, 0, stream>>>(x, emb, Wxh, bxh, bhh, out);
  rnn_kernel<<<dim3(64), 256, 0, stream>>>(Whh, out, hb, fl);
}

// Round 3
// 6518.836 us; speedup vs baseline: 1.5659x; 1.5659x over previous
//
#include <hip/hip_runtime.h>
#include <math.h>

typedef _Float16 half8 __attribute__((ext_vector_type(8)));
typedef float floatx4 __attribute__((ext_vector_type(4)));
typedef unsigned long long u64x2 __attribute__((ext_vector_type(2)));

#define NB 64
#define LQ 512
#define HD 1024

__device__ inline half8 cvt2(const float4 a, const float4 b) {
  half8 h;
  h[0]=(_Float16)a.x; h[1]=(_Float16)a.y; h[2]=(_Float16)a.z; h[3]=(_Float16)a.w;
  h[4]=(_Float16)b.x; h[5]=(_Float16)b.y; h[6]=(_Float16)b.z; h[7]=(_Float16)b.w;
  return h;
}

// Coherent-at-IF$ accessors: relaxed system-scope atomics lower to
// global_load/store ... sc0 sc1 (bypass L1+L2) with compiler-managed waitcnt.
__device__ inline unsigned long long ld_sys64(const void* p) {
  return __hip_atomic_load((const unsigned long long*)p, __ATOMIC_RELAXED,
                           __HIP_MEMORY_SCOPE_SYSTEM);
}
__device__ inline void st_sys16(void* p, _Float16 v) {
  __hip_atomic_store((unsigned short*)p, __builtin_bit_cast(unsigned short, v),
                     __ATOMIC_RELAXED, __HIP_MEMORY_SCOPE_SYSTEM);
}
__device__ inline void vmcnt0() { asm volatile("s_waitcnt vmcnt(0)" ::: "memory"); }

// ---------------------------------------------------------------------------
// GEMM1 (unchanged, verified R1): out[m][o] = emb[x[m]].Wxh[o] + bxh[o]+bhh[o]
// ---------------------------------------------------------------------------
__global__ __launch_bounds__(256) void gemm1_kernel(
    const int* __restrict__ x, const float* __restrict__ emb,
    const float* __restrict__ Wxh, const float* __restrict__ bxh,
    const float* __restrict__ bhh, float* __restrict__ out)
{
  __shared__ alignas(16) _Float16 As[128][72];
  __shared__ alignas(16) _Float16 Bs[128][72];
  const int tid  = threadIdx.x;
  const int lane = tid & 63, wv = tid >> 6;
  const int wm = wv & 1, wn = wv >> 1;
  const int Mbase = blockIdx.x * 128;
  const int Nbase = blockIdx.y * 128;

  const int srow  = tid >> 1;
  const int shalf = tid & 1;
  const size_t erow = (size_t)x[Mbase + srow] * HD;
  const size_t brow = (size_t)(Nbase + srow) * HD;

  floatx4 acc[4][4];
#pragma unroll
  for (int i = 0; i < 4; i++)
#pragma unroll
    for (int j = 0; j < 4; j++) acc[i][j] = (floatx4)0.f;

  for (int c = 0; c < 16; ++c) {
    const int k0 = c * 64 + shalf * 32;
    const float4* ap = (const float4*)(emb + erow + k0);
    const float4* bp = (const float4*)(Wxh + brow + k0);
    float4 av[8], bv[8];
#pragma unroll
    for (int i = 0; i < 8; i++) { av[i] = ap[i]; bv[i] = bp[i]; }
    __syncthreads();
#pragma unroll
    for (int i = 0; i < 4; i++) {
      *(half8*)&As[srow][shalf*32 + i*8] = cvt2(av[2*i], av[2*i+1]);
      *(half8*)&Bs[srow][shalf*32 + i*8] = cvt2(bv[2*i], bv[2*i+1]);
    }
    __syncthreads();
#pragma unroll
    for (int s = 0; s < 2; ++s) {
      const int koff = s*32 + (lane >> 4) * 8;
      half8 af[4], bf[4];
#pragma unroll
      for (int i = 0; i < 4; i++) {
        af[i] = *(const half8*)&As[wm*64 + i*16 + (lane & 15)][koff];
        bf[i] = *(const half8*)&Bs[wn*64 + i*16 + (lane & 15)][koff];
      }
#pragma unroll
      for (int i = 0; i < 4; i++)
#pragma unroll
        for (int j = 0; j < 4; j++)
          acc[i][j] = __builtin_amdgcn_mfma_f32_16x16x32_f16(af[i], bf[j], acc[i][j], 0, 0, 0);
    }
  }
#pragma unroll
  for (int j = 0; j < 4; j++) {
    const int o = Nbase + wn*64 + j*16 + (lane & 15);
    const float bias = bxh[o] + bhh[o];
#pragma unroll
    for (int i = 0; i < 4; i++) {
      const int mb = Mbase + wm*64 + i*16 + ((lane >> 4) * 4);
#pragma unroll
      for (int r = 0; r < 4; r++)
        out[(size_t)(mb + r) * HD + o] = acc[i][j][r] + bias;
    }
  }
}

// ---------------------------------------------------------------------------
// RNN v2b: 32 wgs x 256 thr (4 waves). wg j owns channels [32j,32j+32);
// wave w owns batch rows [16w,16w+16). No fences, no __syncthreads in the
// step loop. Cross-wg data (hb, flags) via relaxed system-scope atomics
// (sc0 sc1, coherent at IF$); publish = s_waitcnt vmcnt(0) + relaxed flag
// store. Ws (f16 W_hh slice) in 64 KB LDS, XOR-swizzled 16B chunks.
// ---------------------------------------------------------------------------
__global__ __launch_bounds__(256, 1) void rnn_kernel(
    const float* __restrict__ Whh, float* __restrict__ out,
    _Float16* __restrict__ hb, int* __restrict__ flags)
{
  __shared__ alignas(16) _Float16 Ws[32 * 1024];   // 64 KB exactly
  const int tid = threadIdx.x, lane = tid & 63, w = tid >> 6;
  const int j = blockIdx.x, obase = j * 32;
  const int col = lane & 15, quad = lane >> 4;
  const int wid = j * 4 + w;                        // per-wave flag id 0..127

  // ---- stage W_hh slice fp32 -> f16, swizzled
  {
    const int o = tid >> 3, t8 = tid & 7;
    const float* src = Whh + (size_t)(obase + o) * HD;
#pragma unroll
    for (int i = 0; i < 16; ++i) {
      const int c16 = t8 * 16 + i;                  // 16B chunk index 0..127
      float4 v0 = *(const float4*)(src + c16 * 8);
      float4 v1 = *(const float4*)(src + c16 * 8 + 4);
      *(half8*)&Ws[o * 1024 + ((c16 ^ (o & 7)) * 8)] = cvt2(v0, v1);
    }
  }
  __syncthreads();                                  // only barrier in the kernel

  const int nbase = 16 * w + quad * 4;              // C-layout row base

  // ---- t = 0: h0 = tanh(xh0)
  {
#pragma unroll
    for (int ct = 0; ct < 2; ++ct) {
      const int o = obase + ct * 16 + col;
#pragma unroll
      for (int r = 0; r < 4; ++r) {
        const int n = nbase + r;
        const size_t oi = (size_t)n * LQ * HD + o;
        float h = tanhf(out[oi]);
        out[oi] = h;
        st_sys16(hb + (size_t)n * HD + o, (_Float16)h);
      }
    }
    vmcnt0();
    if (lane == 0)
      __hip_atomic_store(&flags[wid], 1, __ATOMIC_RELAXED, __HIP_MEMORY_SCOPE_SYSTEM);
  }

  for (int t = 1; t < LQ; ++t) {
    // xh prefetch (wave-private in out, normal cached loads)
    float xh[2][4];
#pragma unroll
    for (int ct = 0; ct < 2; ++ct)
#pragma unroll
      for (int r = 0; r < 4; ++r)
        xh[ct][r] = out[((size_t)(nbase + r) * LQ + t) * HD + obase + ct * 16 + col];

    // ---- wait for all 128 waves to publish step t-1 (poison = negative)
    {
      int spins = 0;
      for (;;) {
        int v0 = __hip_atomic_load(&flags[lane],      __ATOMIC_RELAXED, __HIP_MEMORY_SCOPE_SYSTEM);
        int v1 = __hip_atomic_load(&flags[64 + lane], __ATOMIC_RELAXED, __HIP_MEMORY_SCOPE_SYSTEM);
        if (__all(v0 >= t && v1 >= t)) break;
        if (++spins > (1 << 20)) break;             // wrong > hung
      }
    }

    // ---- A fragments of h_{t-1} from IF$ in MFMA layout (2x8B per chunk)
    const _Float16* hprev = hb + (size_t)((t - 1) & 1) * (NB * HD);
    const _Float16* ap = hprev + (size_t)(16 * w + col) * HD + quad * 8;
    u64x2 a[32];
#pragma unroll
    for (int c = 0; c < 32; ++c) {
      a[c].x = ld_sys64(ap + c * 32);
      a[c].y = ld_sys64(ap + c * 32 + 4);
    }

    // ---- 64 MFMA: 16 rows x 32 cols, K=1024
    floatx4 acc0 = (floatx4)0.f, acc1 = (floatx4)0.f;
#pragma unroll
    for (int c = 0; c < 32; ++c) {
      const int sw = ((4 * c + quad) ^ (col & 7)) * 8;
      half8 b0 = *(const half8*)&Ws[col * 1024 + sw];
      half8 b1 = *(const half8*)&Ws[(16 + col) * 1024 + sw];
      half8 af = __builtin_bit_cast(half8, a[c]);
      acc0 = __builtin_amdgcn_mfma_f32_16x16x32_f16(af, b0, acc0, 0, 0, 0);
      acc1 = __builtin_amdgcn_mfma_f32_16x16x32_f16(af, b1, acc1, 0, 0, 0);
    }

    // ---- epilogue: h = tanh(acc + xh); out cached (private), hb via IF$
    _Float16* hcur = hb + (size_t)(t & 1) * (NB * HD);
#pragma unroll
    for (int ct = 0; ct < 2; ++ct) {
      const floatx4 accv = ct ? acc1 : acc0;
      const int o = obase + ct * 16 + col;
#pragma unroll
      for (int r = 0; r < 4; ++r) {
        const int n = nbase + r;
        float h = tanhf(accv[r] + xh[ct][r]);
        out[((size_t)n * LQ + t) * HD + o] = h;
        st_sys16(hcur + (size_t)n * HD + o, (_Float16)h);
      }
    }
    vmcnt0();                                       // h at IF$ before publish
    if (lane == 0)
      __hip_atomic_store(&flags[wid], t + 1, __ATOMIC_RELAXED, __HIP_MEMORY_SCOPE_SYSTEM);
  }
}

extern "C" void kernel_launch(void* const* d_in, const int* in_sizes, int n_in,
                              void* d_out, int out_size, void* d_ws, size_t ws_size,
                              hipStream_t stream) {
  const int*   x   = (const int*)d_in[0];
  const float* emb = (const float*)d_in[1];
  const float* Whh = (const float*)d_in[2];
  const float* bhh = (const float*)d_in[3];
  const float* Wxh = (const float*)d_in[4];
  const float* bxh = (const float*)d_in[5];
  float* out = (float*)d_out;

  _Float16* hbuf = (_Float16*)d_ws;                  // 2 x 64 x 1024 f16 = 256 KB
  int*      fl   = (int*)((char*)d_ws + 256 * 1024); // 128 per-wave flags

  gemm1_kernel<<<dim3(256, 8), 256, 0, stream>>>(x, emb, Wxh, bxh, bhh, out);
  rnn_kernel<<<dim3(32), 256, 0, stream>>>(Whh, out, hbuf, fl);
}